// Round 1
// baseline (91.820 us; speedup 1.0000x reference)
//
#include <hip/hip_runtime.h>
#include <math.h>

// ThermostatNN: B independent 40-step rollouts of a 2->64->1 MLP plant +
// hysteresis thermostat. One thread per batch element; hidden loop unrolled;
// per-thread invariant c[j] = aux*W1[1][j] + b1[j] hoisted to registers.
// All decision-critical arithmetic uses explicitly-rounded f32 ops (no
// compiler contraction) to track the numpy reference: the temp<=66/78
// comparisons are chaos-amplifying, so rounding fidelity matters.

#define LHID 64
#define NSTEPS 40

__global__ __launch_bounds__(256) void thermostat_kernel(
    const float* __restrict__ x_init,  // (B,4): step, isOn, temp, aux
    const float* __restrict__ W1,      // (2,64) row-major
    const float* __restrict__ b1,      // (64)
    const float* __restrict__ W2,      // (64,1)
    const float* __restrict__ b2,      // (1)
    float* __restrict__ out,           // (40,B)
    int B)
{
    int b = blockIdx.x * blockDim.x + threadIdx.x;
    if (b >= B) return;

    float4 st = reinterpret_cast<const float4*>(x_init)[b];
    float step = st.x;
    float isOn = st.y;
    float temp = st.z;
    float aux  = st.w;
    float bias2 = b2[0];

    // Per-thread invariant part of layer 1: c[j] = aux*W1[1][j] + b1[j]
    float c[LHID];
#pragma unroll
    for (int j = 0; j < LHID; ++j) {
        c[j] = fmaf(aux, W1[LHID + j], b1[j]);
    }

    for (int t = 0; t < NSTEPS; ++t) {
        bool active = step < (float)NSTEPS;

        // ---- plant NN: s = sigmoid(relu([temp,aux]@W1 + b1) @ W2 + b2) ----
        float acc = 0.0f;
#pragma unroll
        for (int j = 0; j < LHID; ++j) {
            float h = fmaf(temp, W1[j], c[j]);   // temp*W1[0][j] + (aux*W1[1][j]+b1[j])
            h = fmaxf(h, 0.0f);                  // relu
            acc = fmaf(h, W2[j], acc);           // dot with W2
        }
        float x = __fadd_rn(acc, bias2);

        // numerically stable sigmoid, matching where(x>=0, 1/(1+e^-x), e^x/(1+e^x))
        float e = expf(-fabsf(x));
        float s;
        if (x >= 0.0f) s = 1.0f / (1.0f + e);
        else           s = e / (1.0f + e);

        // plant = s*10 - 5 ; dtemp = plant*10  (explicit rounding, no contraction)
        float plant = __fsub_rn(__fmul_rn(s, 10.0f), 5.0f);
        float dtemp = __fmul_rn(plant, 10.0f);

        float tn_off = __fadd_rn(temp, dtemp);
        float tn_on  = __fadd_rn(tn_off, 5.0f);

        bool off = (isOn <= 0.5f);
        float temp_new = off ? tn_off : tn_on;
        float isOn_new;
        if (off) isOn_new = (temp_new <= 66.0f) ? 1.0f : isOn;
        else     isOn_new = (temp_new <= 78.0f) ? isOn : 0.0f;

        if (active) {
            temp = temp_new;
            isOn = isOn_new;
            step = __fadd_rn(step, 1.0f);
        }

        out[(size_t)t * B + b] = temp;
    }
}

extern "C" void kernel_launch(void* const* d_in, const int* in_sizes, int n_in,
                              void* d_out, int out_size, void* d_ws, size_t ws_size,
                              hipStream_t stream) {
    const float* x_init = (const float*)d_in[0];
    const float* W1     = (const float*)d_in[1];
    const float* b1     = (const float*)d_in[2];
    const float* W2     = (const float*)d_in[3];
    const float* b2     = (const float*)d_in[4];
    float* out = (float*)d_out;

    int B = in_sizes[0] / 4;
    int threads = 256;
    int blocks = (B + threads - 1) / threads;
    thermostat_kernel<<<blocks, threads, 0, stream>>>(x_init, W1, b1, W2, b2, out, B);
}